// Round 1
// 390.414 us; speedup vs baseline: 1.0731x; 1.0731x over previous
//
#include <hip/hip_runtime.h>
#include <hip/hip_bf16.h>
#include <cstdint>

#define DIM 1024
#define BATCH 4
#define SEQ 8192
#define M_TOTAL (BATCH * SEQ)   // 32768

#define CH 64               // number of chunks for the scan
#define CL (SEQ / CH)       // chunk length = 128

using bf16 = __hip_bfloat16;
typedef __attribute__((ext_vector_type(4))) float f32x4;
typedef __attribute__((ext_vector_type(8))) __bf16 bf16x8;

#define NT (DIM / 64)       // 16 K-tiles of BK=64
#define NI (NT / 2)         // 8 outer iterations (2 K-tiles each)

// Raw barrier (no vmcnt drain!) + compiler memory fence.
#define BAR() asm volatile("s_barrier" ::: "memory")
#define WAIT_LGKM0()                                    \
  do {                                                  \
    asm volatile("s_waitcnt lgkmcnt(0)" ::: "memory");  \
    __builtin_amdgcn_sched_barrier(0);                  \
  } while (0)
#define WAIT_VM(n) asm volatile("s_waitcnt vmcnt(" #n ")" ::: "memory")

// ---------------------------------------------------------------------------
// fp32 -> bf16 conversion for x, w_in, w_out in ONE kernel
// ---------------------------------------------------------------------------
__global__ void convert_all(const float* __restrict__ x, bf16* __restrict__ xb,
                            const float* __restrict__ w1, bf16* __restrict__ w1b,
                            const float* __restrict__ w2, bf16* __restrict__ w2b,
                            long n4x, long n4w) {
    long i = blockIdx.x * (long)blockDim.x + threadIdx.x;
    const float* in;
    bf16* out;
    long off;
    if (i < n4x)              { in = x;  out = xb;  off = i; }
    else if (i < n4x + n4w)   { in = w1; out = w1b; off = i - n4x; }
    else if (i < n4x + 2*n4w) { in = w2; out = w2b; off = i - n4x - n4w; }
    else return;
    const float4 v = ((const float4*)in)[off];
    __hip_bfloat162* o = (__hip_bfloat162*)(out + off * 4);
    o[0] = __float22bfloat162_rn(make_float2(v.x, v.y));
    o[1] = __float22bfloat162_rn(make_float2(v.z, v.w));
}

// ---------------------------------------------------------------------------
// Stage one half-tile (128 rows x 64 cols bf16 = 16KB) via global_load_lds.
// LDS layout: chunk(row, kcs) = row*8 + kcs, 16B chunks, with the XOR swizzle
// kcs = kc_global ^ (row & 7) applied by pre-swizzling the GLOBAL source
// address (LDS dest stays linear: wave-uniform base + lane*16).
// Per thread: 2 x global_load_lds(16B). 512 threads cover 1024 chunks.
// ---------------------------------------------------------------------------
__device__ __forceinline__ void stage_half(const bf16* __restrict__ g,
                                           char* ldsbase, int tid) {
    const int w = tid >> 6, l = tid & 63;
    const int kc = (l & 7) ^ ((l >> 3) & 7);   // pre-swizzled global k-chunk
#pragma unroll
    for (int j = 0; j < 2; j++) {
        const int idx = (w * 2 + j) * 64 + l;          // LDS chunk index
        const int row = w * 16 + j * 8 + (l >> 3);     // row&7 == (l>>3)&7
        const bf16* src = g + (size_t)row * DIM + kc * 8;
        __builtin_amdgcn_global_load_lds(
            (const __attribute__((address_space(1))) void*)src,
            (__attribute__((address_space(3))) void*)(ldsbase + idx * 16),
            16, 0, 0);
    }
}

// ---------------------------------------------------------------------------
// 256x256 8-phase GEMM: C = A * B^T + bias. A:[M][K]=[32768][1024] bf16,
// B:[N][K]=[1024][1024] bf16. 512 threads = 8 waves (2M x 4N), per-wave
// output 128x64 as 8x4 frags of mfma_f32_16x16x32_bf16. BK=64, 2 K-tiles
// per iteration, 8 phases each {ds_read subtile | stage 1 half-tile | bar |
// lgkm0 | setprio1 16xMFMA setprio0 | bar}, counted vmcnt(4) once per K-tile.
// LDS 128KiB: buf0 @0 (A.h0/A.h1/B.h0/B.h1 16KB each), buf1 @64K.
// OUT_MODE 0: bf16 out + FUSED chunk-local scan (writes S); 1: fp32 out.
// ---------------------------------------------------------------------------
template <int OUT_MODE>
__global__ __launch_bounds__(512, 2) void gemm256(
    const bf16* __restrict__ A, const bf16* __restrict__ B,
    const float* __restrict__ bias, void* __restrict__ C,
    const float* __restrict__ acoef, const float* __restrict__ bcoef,
    float* __restrict__ S) {
    __shared__ __align__(16) char lds[131072];

    const int tid  = threadIdx.x;
    const int wave = tid >> 6;
    const int l    = tid & 63;

    // XCD-aware bijective swizzle: 512 blocks = 8 xcd x (16 bm x 4 bn),
    // bn fast within XCD -> A-tile (512KB) reused from per-XCD L2.
    const int orig = blockIdx.x;
    const int xcd  = orig & 7;
    const int li   = orig >> 3;
    const int bm   = xcd * 16 + (li >> 2);   // 0..127
    const int bn   = li & 3;                 // 0..3

    const bf16* Abase = A + (size_t)bm * 256 * DIM;
    const bf16* Bbase = B + (size_t)bn * 256 * DIM;

    // Per-wave LDS windows. A-half = wave>>2; B-quarter = wave&3.
    char* pa0 = lds + (wave >> 2) * 16384;
    char* pb0 = lds + 32768 + ((wave & 3) >> 1) * 16384 + (wave & 1) * 8192;
    char* pa1 = pa0 + 65536;
    char* pb1 = pb0 + 65536;

    // ds_read offsets: frag (f, ks): addr = base + f*2048 + rl*128
    //   + (((ks*4 + lg) ^ r7) << 4).  16 rows / 8 slots -> 2-way (free).
    const int rl = l & 15;
    const int lg = l >> 4;
    const int r7 = l & 7;
    const int ao0 = rl * 128 + ((lg ^ r7) << 4);
    const int ao1 = rl * 128 + (((4 + lg) ^ r7) << 4);

    f32x4 acc[8][4];
#pragma unroll
    for (int m = 0; m < 8; m++)
#pragma unroll
        for (int n = 0; n < 4; n++)
#pragma unroll
            for (int r = 0; r < 4; r++) acc[m][n][r] = 0.f;

    bf16x8 af[4][2], bfr[4][2];

#define READ_A4(PA, FMB)                                                   \
    _Pragma("unroll") for (int m_ = 0; m_ < 4; m_++) {                     \
        af[m_][0] = *(const bf16x8*)((PA) + (FMB + m_) * 2048 + ao0);      \
        af[m_][1] = *(const bf16x8*)((PA) + (FMB + m_) * 2048 + ao1);      \
    }
#define READ_B2(PB, FNB)                                                   \
    _Pragma("unroll") for (int n_ = 0; n_ < 2; n_++) {                     \
        bfr[FNB + n_][0] = *(const bf16x8*)((PB) + (FNB + n_) * 2048 + ao0); \
        bfr[FNB + n_][1] = *(const bf16x8*)((PB) + (FNB + n_) * 2048 + ao1); \
    }
#define MFMA16(MB, NB2)                                                    \
    __builtin_amdgcn_s_setprio(1);                                         \
    _Pragma("unroll") for (int m_ = 0; m_ < 4; m_++)                       \
    _Pragma("unroll") for (int n_ = 0; n_ < 2; n_++)                       \
    _Pragma("unroll") for (int k_ = 0; k_ < 2; k_++)                       \
        acc[MB + m_][NB2 + n_] = __builtin_amdgcn_mfma_f32_16x16x32_bf16(  \
            af[m_][k_], bfr[NB2 + n_][k_], acc[MB + m_][NB2 + n_], 0, 0, 0); \
    __builtin_amdgcn_s_setprio(0);

    // Prologue: tile0 (A0,A1,B0,B1) + tile1's B halves. vmcnt(4) leaves only
    // B(1) in flight -> tile0 fully landed.
    stage_half(Abase,                          lds +     0, tid);
    stage_half(Abase + (size_t)128 * DIM,      lds + 16384, tid);
    stage_half(Bbase,                          lds + 32768, tid);
    stage_half(Bbase + (size_t)128 * DIM,      lds + 49152, tid);
    stage_half(Bbase + 64,                     lds + 65536 + 32768, tid);
    stage_half(Bbase + (size_t)128 * DIM + 64, lds + 65536 + 49152, tid);
    WAIT_VM(4);
    BAR();

    // Stage schedule (WAR-safe: every overwrite is >=1 barrier after its
    // region's last ds_read; RAW guarded by vmcnt(4) at phases 4 & 8):
    //  ph1:A0(t+1) ph2:A1(t+1) ph3:B0(t+2) ph4:B1(t+2)+VM
    //  ph5:A0(t+2) ph6:A1(t+2) ph7:B0(t+3) ph8:B1(t+3)+VM
    for (int i = 0; i < NI; ++i) {
        const bool last = (i == NI - 1);
        const size_t kt1 = (size_t)(2 * i + 1) * 64;
        const size_t kt2 = kt1 + 64;
        const size_t kt3 = kt1 + 128;

        // ---- window 0: K-tile t from buf0 ----
        READ_A4(pa0, 0); READ_B2(pb0, 0);                       // ph1
        stage_half(Abase + kt1, lds + 65536, tid);
        BAR(); WAIT_LGKM0(); MFMA16(0, 0); BAR();

        READ_B2(pb0, 2);                                        // ph2
        stage_half(Abase + (size_t)128 * DIM + kt1, lds + 65536 + 16384, tid);
        BAR(); WAIT_LGKM0(); MFMA16(0, 2); BAR();

        READ_A4(pa0, 4);                                        // ph3
        if (!last) stage_half(Bbase + kt2, lds + 32768, tid);
        BAR(); WAIT_LGKM0(); MFMA16(4, 0); BAR();

        if (!last)                                              // ph4
            stage_half(Bbase + (size_t)128 * DIM + kt2, lds + 49152, tid);
        BAR(); WAIT_LGKM0(); MFMA16(4, 2);
        if (last) { WAIT_VM(0); } else { WAIT_VM(4); }
        BAR();

        // ---- window 1: K-tile t+1 from buf1 ----
        READ_A4(pa1, 0); READ_B2(pb1, 0);                       // ph5
        if (!last) stage_half(Abase + kt2, lds + 0, tid);
        BAR(); WAIT_LGKM0(); MFMA16(0, 0); BAR();

        READ_B2(pb1, 2);                                        // ph6
        if (!last) stage_half(Abase + (size_t)128 * DIM + kt2, lds + 16384, tid);
        BAR(); WAIT_LGKM0(); MFMA16(0, 2); BAR();

        READ_A4(pa1, 4);                                        // ph7
        if (!last) stage_half(Bbase + kt3, lds + 65536 + 32768, tid);
        BAR(); WAIT_LGKM0(); MFMA16(4, 0); BAR();

        if (!last)                                              // ph8
            stage_half(Bbase + (size_t)128 * DIM + kt3, lds + 65536 + 49152, tid);
        BAR(); WAIT_LGKM0(); MFMA16(4, 2);
        if (!last) { WAIT_VM(4); }
        BAR();
    }

    // Epilogue. 16x16 C/D layout (m89-verified): col = lane&15,
    // row = (lane>>4)*4 + reg.
    const int wm = (wave >> 2) * 128;
    const int wn = (wave & 3) * 64;
    const long mb = (long)bm * 256 + wm;
    const int nb = bn * 256 + wn;
    const int crow = lg * 4;

    float bv[4];
#pragma unroll
    for (int n = 0; n < 4; n++) bv[n] = bias[nb + n * 16 + rl];

    if (OUT_MODE == 1) {
        float* O = (float*)C;
#pragma unroll
        for (int m = 0; m < 8; m++)
#pragma unroll
            for (int n = 0; n < 4; n++) {
                const int col = nb + n * 16 + rl;
#pragma unroll
                for (int r = 0; r < 4; r++)
                    O[(mb + m * 16 + crow + r) * (long)DIM + col] =
                        acc[m][n][r] + bv[n];
            }
    } else {
        // bf16 h out + fused chunk-local scan. Tile rows 256 = exactly 2
        // scan chunks (CL=128); LDS (dead after main loop) holds the bf16
        // h-tile [256 rows][256 cols], row stride 512B, col bytes XOR-
        // swizzled by ((row>>2)&7)<<4 (conflict-free writes AND reads).
        bf16* H = (bf16*)C;
#pragma unroll
        for (int m = 0; m < 8; m++)
#pragma unroll
            for (int n = 0; n < 4; n++) {
                const int col  = nb + n * 16 + rl;
                const int lcol = wn + n * 16 + rl;
#pragma unroll
                for (int r = 0; r < 4; r++) {
                    const int lrow = wm + m * 16 + crow + r;
                    const bf16 hv = __float2bfloat16(acc[m][n][r] + bv[n]);
                    H[(mb + m * 16 + crow + r) * (long)DIM + col] = hv;
                    const int cb = (lcol * 2) ^ (((lrow >> 2) & 7) << 4);
                    *(bf16*)(lds + lrow * 512 + cb) = hv;
                }
            }
        asm volatile("s_waitcnt lgkmcnt(0)" ::: "memory");
        BAR();
        // 512 threads = 2 chunks x 256 cols; 128-step serial scan each.
        const int c   = tid & 255;
        const int ch2 = tid >> 8;
        const int d   = bn * 256 + c;
        const float Ad = 1.f / (1.f + expf(-acoef[d]));
        const float bd = bcoef[d];
        float s = 0.f;
#pragma unroll 8
        for (int t = 0; t < CL; t++) {
            const int lrow = ch2 * 128 + t;
            const int cb = (c * 2) ^ (((lrow >> 2) & 7) << 4);
            const float v = __bfloat162float(*(const bf16*)(lds + lrow * 512 + cb));
            s = Ad * s + bd * v;
        }
        S[((long)bm * 2 + ch2) * DIM + d] = s;
    }
#undef READ_A4
#undef READ_B2
#undef MFMA16
}

// ---------------------------------------------------------------------------
// Pass 3 (combine folded in): recompute incoming carry from preceding chunks'
// S (L2-hot), then replay the chunk writing y over h in place.
// ---------------------------------------------------------------------------
__global__ __launch_bounds__(512) void scan_pass3(
    bf16* __restrict__ h, const float* __restrict__ a,
    const float* __restrict__ bcoef, const float* __restrict__ S) {
    const int d2 = threadIdx.x;
    const int blk = blockIdx.x;
    const int b = blk / CH, c = blk % CH;
    const float A0 = 1.f / (1.f + expf(-a[2 * d2]));
    const float A1 = 1.f / (1.f + expf(-a[2 * d2 + 1]));
    const float b0 = bcoef[2 * d2];
    const float b1 = bcoef[2 * d2 + 1];
    float Ap0 = A0, Ap1 = A1;              // A^CL via repeated squaring, CL=128
#pragma unroll
    for (int i = 0; i < 7; i++) { Ap0 *= Ap0; Ap1 *= Ap1; }

    float c0 = 0.f, c1 = 0.f;
    const float2* Sp = (const float2*)(S + (long)b * CH * DIM) + d2;
    for (int i0 = 0; i0 < c; i0 += 8) {
        float2 sv[8];
        int nn = (c - i0 < 8) ? (c - i0) : 8;
#pragma unroll 8
        for (int j = 0; j < 8; j++)
            if (j < nn) sv[j] = Sp[(long)(i0 + j) * (DIM / 2)];
#pragma unroll 8
        for (int j = 0; j < 8; j++)
            if (j < nn) { c0 = Ap0 * c0 + sv[j].x; c1 = Ap1 * c1 + sv[j].y; }
    }

    float s0 = c0, s1 = c1;
    __hip_bfloat162* hp =
        (__hip_bfloat162*)(h + ((long)b * SEQ + (long)c * CL) * DIM) + d2;
#pragma unroll 8
    for (int t = 0; t < CL; t++) {
        float2 v = __bfloat1622float2(hp[(long)t * (DIM / 2)]);
        s0 = A0 * s0 + b0 * v.x;
        s1 = A1 * s1 + b1 * v.y;
        hp[(long)t * (DIM / 2)] = __float22bfloat162_rn(make_float2(s0, s1));
    }
}

// ---------------------------------------------------------------------------
extern "C" void kernel_launch(void* const* d_in, const int* in_sizes, int n_in,
                              void* d_out, int out_size, void* d_ws,
                              size_t ws_size, hipStream_t stream) {
    const float* x     = (const float*)d_in[0];
    const float* w_in  = (const float*)d_in[1];
    const float* b_in  = (const float*)d_in[2];
    const float* a     = (const float*)d_in[3];
    const float* bcoef = (const float*)d_in[4];
    const float* w_out = (const float*)d_in[5];
    const float* b_out = (const float*)d_in[6];
    float* out = (float*)d_out;

    char* ws = (char*)d_ws;
    bf16* xb  = (bf16*)ws;  ws += (size_t)M_TOTAL * DIM * 2;    // 64 MB
    bf16* wib = (bf16*)ws;  ws += (size_t)DIM * DIM * 2;        // 2 MB
    bf16* wob = (bf16*)ws;  ws += (size_t)DIM * DIM * 2;        // 2 MB
    bf16* h   = (bf16*)ws;  ws += (size_t)M_TOTAL * DIM * 2;    // 64 MB (h then y)
    float* S  = (float*)ws; ws += (size_t)BATCH * CH * DIM * 4; // 1 MB

    // 1. fp32 -> bf16 conversions (single kernel)
    {
        long n4x = (long)M_TOTAL * DIM / 4;
        long n4w = (long)DIM * DIM / 4;
        long total = n4x + 2 * n4w;
        convert_all<<<(int)((total + 255) / 256), 256, 0, stream>>>(
            x, xb, w_in, wib, w_out, wob, n4x, n4w);
    }

    const int nblocks = (M_TOTAL / 256) * (DIM / 256);  // 512

    // 2. h = x @ w_in^T + b_in (bf16) + fused chunk-local scan -> S
    gemm256<0><<<nblocks, 512, 0, stream>>>(xb, wib, b_in, h, a, bcoef, S);

    // 3. carry + replay (y overwrites h, bf16)
    scan_pass3<<<BATCH * CH, 512, 0, stream>>>(h, a, bcoef, S);

    // 4. out = y @ w_out^T + b_out  (fp32 out)
    gemm256<1><<<nblocks, 512, 0, stream>>>(h, wob, b_out, out,
                                            nullptr, nullptr, nullptr);
}

// Round 2
// 382.435 us; speedup vs baseline: 1.0955x; 1.0209x over previous
//
#include <hip/hip_runtime.h>
#include <hip/hip_bf16.h>
#include <cstdint>

#define DIM 1024
#define BATCH 4
#define SEQ 8192
#define M_TOTAL (BATCH * SEQ)   // 32768

#define CH 64               // number of chunks for the scan
#define CL (SEQ / CH)       // chunk length = 128

using bf16 = __hip_bfloat16;
typedef __attribute__((ext_vector_type(4))) float f32x4;
typedef __attribute__((ext_vector_type(8))) __bf16 bf16x8;

#define NT (DIM / 64)       // 16 K-tiles of BK=64
#define NI (NT / 2)         // 8 outer iterations (2 K-tiles each)

// Template-faithful sync idioms (m201): builtin barrier, BARE waitcnt asm.
// NO "memory" clobbers — a clobber makes SIInsertWaitcnts treat the asm as
// a memory op and emit s_waitcnt vmcnt(0) lgkmcnt(0) before it, draining
// the counted-vmcnt pipeline every phase (round-1 null result).
#define BAR()      __builtin_amdgcn_s_barrier()
#define LGKM0()    asm volatile("s_waitcnt lgkmcnt(0)")
#define WAIT_VM(n) asm volatile("s_waitcnt vmcnt(" #n ")")

// ---------------------------------------------------------------------------
// fp32 -> bf16 conversion for x, w_in, w_out in ONE kernel
// ---------------------------------------------------------------------------
__global__ void convert_all(const float* __restrict__ x, bf16* __restrict__ xb,
                            const float* __restrict__ w1, bf16* __restrict__ w1b,
                            const float* __restrict__ w2, bf16* __restrict__ w2b,
                            long n4x, long n4w) {
    long i = blockIdx.x * (long)blockDim.x + threadIdx.x;
    const float* in;
    bf16* out;
    long off;
    if (i < n4x)              { in = x;  out = xb;  off = i; }
    else if (i < n4x + n4w)   { in = w1; out = w1b; off = i - n4x; }
    else if (i < n4x + 2*n4w) { in = w2; out = w2b; off = i - n4x - n4w; }
    else return;
    const float4 v = ((const float4*)in)[off];
    __hip_bfloat162* o = (__hip_bfloat162*)(out + off * 4);
    o[0] = __float22bfloat162_rn(make_float2(v.x, v.y));
    o[1] = __float22bfloat162_rn(make_float2(v.z, v.w));
}

// ---------------------------------------------------------------------------
// Stage one half-tile (128 rows x 64 cols bf16 = 16KB) via global_load_lds.
// LDS layout: chunk(row, kcs) = row*8 + kcs, 16B chunks, with the XOR swizzle
// kcs = kc_global ^ (row & 7) applied by pre-swizzling the GLOBAL source
// address (LDS dest stays linear: wave-uniform base + lane*16).
// Per thread: 2 x global_load_lds(16B). 512 threads cover 1024 chunks.
// ---------------------------------------------------------------------------
__device__ __forceinline__ void stage_half(const bf16* __restrict__ g,
                                           char* ldsbase, int tid) {
    const int w = tid >> 6, l = tid & 63;
    const int kc = (l & 7) ^ ((l >> 3) & 7);   // pre-swizzled global k-chunk
#pragma unroll
    for (int j = 0; j < 2; j++) {
        const int idx = (w * 2 + j) * 64 + l;          // LDS chunk index
        const int row = w * 16 + j * 8 + (l >> 3);     // row&7 == (l>>3)&7
        const bf16* src = g + (size_t)row * DIM + kc * 8;
        __builtin_amdgcn_global_load_lds(
            (const __attribute__((address_space(1))) void*)src,
            (__attribute__((address_space(3))) void*)(ldsbase + idx * 16),
            16, 0, 0);
    }
}

// ---------------------------------------------------------------------------
// 256x256 8-phase GEMM: C = A * B^T + bias. A:[M][K]=[32768][1024] bf16,
// B:[N][K]=[1024][1024] bf16. 512 threads = 8 waves (2M x 4N), per-wave
// output 128x64 as 8x4 frags of mfma_f32_16x16x32_bf16. BK=64, 2 K-tiles
// per iteration, 8 phases each {ds_read subtile | stage 1 half-tile | bar |
// lgkm0 | setprio1 16xMFMA setprio0 | bar}, counted vmcnt(4) once per K-tile.
// LDS 128KiB: buf0 @0 (A.h0/A.h1/B.h0/B.h1 16KB each), buf1 @64K.
// OUT_MODE 0: bf16 out + FUSED chunk-local scan (writes S); 1: fp32 out.
// ---------------------------------------------------------------------------
template <int OUT_MODE>
__global__ __launch_bounds__(512, 2) void gemm256(
    const bf16* __restrict__ A, const bf16* __restrict__ B,
    const float* __restrict__ bias, void* __restrict__ C,
    const float* __restrict__ acoef, const float* __restrict__ bcoef,
    float* __restrict__ S) {
    __shared__ __align__(16) char lds[131072];

    const int tid  = threadIdx.x;
    const int wave = tid >> 6;
    const int l    = tid & 63;

    // XCD-aware bijective swizzle: 512 blocks = 8 xcd x (16 bm x 4 bn),
    // bn fast within XCD -> A-tile reused from per-XCD L2.
    const int orig = blockIdx.x;
    const int xcd  = orig & 7;
    const int li   = orig >> 3;
    const int bm   = xcd * 16 + (li >> 2);   // 0..127
    const int bn   = li & 3;                 // 0..3

    const bf16* Abase = A + (size_t)bm * 256 * DIM;
    const bf16* Bbase = B + (size_t)bn * 256 * DIM;

    // Per-wave LDS windows. A-half = wave>>2; B-quarter = wave&3.
    char* pa0 = lds + (wave >> 2) * 16384;
    char* pb0 = lds + 32768 + ((wave & 3) >> 1) * 16384 + (wave & 1) * 8192;
    char* pa1 = pa0 + 65536;
    char* pb1 = pb0 + 65536;

    // ds_read offsets: frag (f, ks): addr = base + f*2048 + rl*128
    //   + (((ks*4 + lg) ^ r7) << 4).  16 rows / 8 slots -> 2-way (free).
    const int rl = l & 15;
    const int lg = l >> 4;
    const int r7 = l & 7;
    const int ao0 = rl * 128 + ((lg ^ r7) << 4);
    const int ao1 = rl * 128 + (((4 + lg) ^ r7) << 4);

    f32x4 acc[8][4];
#pragma unroll
    for (int m = 0; m < 8; m++)
#pragma unroll
        for (int n = 0; n < 4; n++)
#pragma unroll
            for (int r = 0; r < 4; r++) acc[m][n][r] = 0.f;

    bf16x8 af[4][2], bfr[4][2];

#define READ_A4(PA, FMB)                                                   \
    _Pragma("unroll") for (int m_ = 0; m_ < 4; m_++) {                     \
        af[m_][0] = *(const bf16x8*)((PA) + (FMB + m_) * 2048 + ao0);      \
        af[m_][1] = *(const bf16x8*)((PA) + (FMB + m_) * 2048 + ao1);      \
    }
#define READ_B2(PB, FNB)                                                   \
    _Pragma("unroll") for (int n_ = 0; n_ < 2; n_++) {                     \
        bfr[FNB + n_][0] = *(const bf16x8*)((PB) + (FNB + n_) * 2048 + ao0); \
        bfr[FNB + n_][1] = *(const bf16x8*)((PB) + (FNB + n_) * 2048 + ao1); \
    }
#define MFMA16(MB, NB2)                                                    \
    __builtin_amdgcn_s_setprio(1);                                         \
    _Pragma("unroll") for (int m_ = 0; m_ < 4; m_++)                       \
    _Pragma("unroll") for (int n_ = 0; n_ < 2; n_++)                       \
    _Pragma("unroll") for (int k_ = 0; k_ < 2; k_++)                       \
        acc[MB + m_][NB2 + n_] = __builtin_amdgcn_mfma_f32_16x16x32_bf16(  \
            af[m_][k_], bfr[NB2 + n_][k_], acc[MB + m_][NB2 + n_], 0, 0, 0); \
    __builtin_amdgcn_s_setprio(0);

    // Prologue: tile0 (A0,A1,B0,B1) + tile1's B halves. vmcnt(4) leaves only
    // B(1) in flight -> tile0 fully landed.
    stage_half(Abase,                          lds +     0, tid);
    stage_half(Abase + (size_t)128 * DIM,      lds + 16384, tid);
    stage_half(Bbase,                          lds + 32768, tid);
    stage_half(Bbase + (size_t)128 * DIM,      lds + 49152, tid);
    stage_half(Bbase + 64,                     lds + 65536 + 32768, tid);
    stage_half(Bbase + (size_t)128 * DIM + 64, lds + 65536 + 49152, tid);
    WAIT_VM(4);
    BAR();

    // Stage schedule (WAR-safe: every overwrite is >=1 barrier after its
    // region's last ds_read; RAW guarded by vmcnt(4) at phases 4 & 8):
    //  ph1:A0(t+1) ph2:A1(t+1) ph3:B0(t+2) ph4:B1(t+2)+VM
    //  ph5:A0(t+2) ph6:A1(t+2) ph7:B0(t+3) ph8:B1(t+3)+VM
    for (int i = 0; i < NI; ++i) {
        const bool last = (i == NI - 1);
        const size_t kt1 = (size_t)(2 * i + 1) * 64;
        const size_t kt2 = kt1 + 64;
        const size_t kt3 = kt1 + 128;

        // ---- window 0: K-tile t from buf0 ----
        READ_A4(pa0, 0); READ_B2(pb0, 0);                       // ph1
        stage_half(Abase + kt1, lds + 65536, tid);
        BAR(); LGKM0(); MFMA16(0, 0); BAR();

        READ_B2(pb0, 2);                                        // ph2
        stage_half(Abase + (size_t)128 * DIM + kt1, lds + 65536 + 16384, tid);
        BAR(); LGKM0(); MFMA16(0, 2); BAR();

        READ_A4(pa0, 4);                                        // ph3
        if (!last) stage_half(Bbase + kt2, lds + 32768, tid);
        BAR(); LGKM0(); MFMA16(4, 0); BAR();

        if (!last)                                              // ph4
            stage_half(Bbase + (size_t)128 * DIM + kt2, lds + 49152, tid);
        BAR(); LGKM0(); MFMA16(4, 2);
        if (last) { WAIT_VM(0); } else { WAIT_VM(4); }
        BAR();

        // ---- window 1: K-tile t+1 from buf1 ----
        READ_A4(pa1, 0); READ_B2(pb1, 0);                       // ph5
        if (!last) stage_half(Abase + kt2, lds + 0, tid);
        BAR(); LGKM0(); MFMA16(0, 0); BAR();

        READ_B2(pb1, 2);                                        // ph6
        if (!last) stage_half(Abase + (size_t)128 * DIM + kt2, lds + 16384, tid);
        BAR(); LGKM0(); MFMA16(0, 2); BAR();

        READ_A4(pa1, 4);                                        // ph7
        if (!last) stage_half(Bbase + kt3, lds + 65536 + 32768, tid);
        BAR(); LGKM0(); MFMA16(4, 0); BAR();

        if (!last)                                              // ph8
            stage_half(Bbase + (size_t)128 * DIM + kt3, lds + 65536 + 49152, tid);
        BAR(); LGKM0(); MFMA16(4, 2);
        if (!last) { WAIT_VM(4); }
        BAR();
    }

    // Epilogue. 16x16 C/D layout (m89-verified): col = lane&15,
    // row = (lane>>4)*4 + reg.
    const int wm = (wave >> 2) * 128;
    const int wn = (wave & 3) * 64;
    const long mb = (long)bm * 256 + wm;
    const int nb = bn * 256 + wn;
    const int crow = lg * 4;

    float bv[4];
#pragma unroll
    for (int n = 0; n < 4; n++) bv[n] = bias[nb + n * 16 + rl];

    if (OUT_MODE == 1) {
        float* O = (float*)C;
#pragma unroll
        for (int m = 0; m < 8; m++)
#pragma unroll
            for (int n = 0; n < 4; n++) {
                const int col = nb + n * 16 + rl;
#pragma unroll
                for (int r = 0; r < 4; r++)
                    O[(mb + m * 16 + crow + r) * (long)DIM + col] =
                        acc[m][n][r] + bv[n];
            }
    } else {
        // bf16 h out + fused chunk-local scan. Tile rows 256 = exactly 2
        // scan chunks (CL=128); LDS (dead after main loop) holds the bf16
        // h-tile [256 rows][256 cols], row stride 512B, col bytes XOR-
        // swizzled by ((row>>2)&7)<<4 (conflict-free writes AND reads).
        bf16* H = (bf16*)C;
#pragma unroll
        for (int m = 0; m < 8; m++)
#pragma unroll
            for (int n = 0; n < 4; n++) {
                const int col  = nb + n * 16 + rl;
                const int lcol = wn + n * 16 + rl;
#pragma unroll
                for (int r = 0; r < 4; r++) {
                    const int lrow = wm + m * 16 + crow + r;
                    const bf16 hv = __float2bfloat16(acc[m][n][r] + bv[n]);
                    H[(mb + m * 16 + crow + r) * (long)DIM + col] = hv;
                    const int cb = (lcol * 2) ^ (((lrow >> 2) & 7) << 4);
                    *(bf16*)(lds + lrow * 512 + cb) = hv;
                }
            }
        __syncthreads();   // once per block: full drain is fine here
        // 512 threads = 2 chunks x 256 cols; 128-step serial scan each.
        const int c   = tid & 255;
        const int ch2 = tid >> 8;
        const int d   = bn * 256 + c;
        const float Ad = 1.f / (1.f + expf(-acoef[d]));
        const float bd = bcoef[d];
        float s = 0.f;
#pragma unroll 8
        for (int t = 0; t < CL; t++) {
            const int lrow = ch2 * 128 + t;
            const int cb = (c * 2) ^ (((lrow >> 2) & 7) << 4);
            const float v = __bfloat162float(*(const bf16*)(lds + lrow * 512 + cb));
            s = Ad * s + bd * v;
        }
        S[((long)bm * 2 + ch2) * DIM + d] = s;
    }
#undef READ_A4
#undef READ_B2
#undef MFMA16
}

// ---------------------------------------------------------------------------
// Pass 3 (combine folded in): recompute incoming carry from preceding chunks'
// S (L2-hot), then replay the chunk writing y over h in place.
// ---------------------------------------------------------------------------
__global__ __launch_bounds__(512) void scan_pass3(
    bf16* __restrict__ h, const float* __restrict__ a,
    const float* __restrict__ bcoef, const float* __restrict__ S) {
    const int d2 = threadIdx.x;
    const int blk = blockIdx.x;
    const int b = blk / CH, c = blk % CH;
    const float A0 = 1.f / (1.f + expf(-a[2 * d2]));
    const float A1 = 1.f / (1.f + expf(-a[2 * d2 + 1]));
    const float b0 = bcoef[2 * d2];
    const float b1 = bcoef[2 * d2 + 1];
    float Ap0 = A0, Ap1 = A1;              // A^CL via repeated squaring, CL=128
#pragma unroll
    for (int i = 0; i < 7; i++) { Ap0 *= Ap0; Ap1 *= Ap1; }

    float c0 = 0.f, c1 = 0.f;
    const float2* Sp = (const float2*)(S + (long)b * CH * DIM) + d2;
    for (int i0 = 0; i0 < c; i0 += 8) {
        float2 sv[8];
        int nn = (c - i0 < 8) ? (c - i0) : 8;
#pragma unroll 8
        for (int j = 0; j < 8; j++)
            if (j < nn) sv[j] = Sp[(long)(i0 + j) * (DIM / 2)];
#pragma unroll 8
        for (int j = 0; j < 8; j++)
            if (j < nn) { c0 = Ap0 * c0 + sv[j].x; c1 = Ap1 * c1 + sv[j].y; }
    }

    float s0 = c0, s1 = c1;
    __hip_bfloat162* hp =
        (__hip_bfloat162*)(h + ((long)b * SEQ + (long)c * CL) * DIM) + d2;
#pragma unroll 8
    for (int t = 0; t < CL; t++) {
        float2 v = __bfloat1622float2(hp[(long)t * (DIM / 2)]);
        s0 = A0 * s0 + b0 * v.x;
        s1 = A1 * s1 + b1 * v.y;
        hp[(long)t * (DIM / 2)] = __float22bfloat162_rn(make_float2(s0, s1));
    }
}

// ---------------------------------------------------------------------------
extern "C" void kernel_launch(void* const* d_in, const int* in_sizes, int n_in,
                              void* d_out, int out_size, void* d_ws,
                              size_t ws_size, hipStream_t stream) {
    const float* x     = (const float*)d_in[0];
    const float* w_in  = (const float*)d_in[1];
    const float* b_in  = (const float*)d_in[2];
    const float* a     = (const float*)d_in[3];
    const float* bcoef = (const float*)d_in[4];
    const float* w_out = (const float*)d_in[5];
    const float* b_out = (const float*)d_in[6];
    float* out = (float*)d_out;

    char* ws = (char*)d_ws;
    bf16* xb  = (bf16*)ws;  ws += (size_t)M_TOTAL * DIM * 2;    // 64 MB
    bf16* wib = (bf16*)ws;  ws += (size_t)DIM * DIM * 2;        // 2 MB
    bf16* wob = (bf16*)ws;  ws += (size_t)DIM * DIM * 2;        // 2 MB
    bf16* h   = (bf16*)ws;  ws += (size_t)M_TOTAL * DIM * 2;    // 64 MB (h then y)
    float* S  = (float*)ws; ws += (size_t)BATCH * CH * DIM * 4; // 1 MB

    // 1. fp32 -> bf16 conversions (single kernel)
    {
        long n4x = (long)M_TOTAL * DIM / 4;
        long n4w = (long)DIM * DIM / 4;
        long total = n4x + 2 * n4w;
        convert_all<<<(int)((total + 255) / 256), 256, 0, stream>>>(
            x, xb, w_in, wib, w_out, wob, n4x, n4w);
    }

    const int nblocks = (M_TOTAL / 256) * (DIM / 256);  // 512

    // 2. h = x @ w_in^T + b_in (bf16) + fused chunk-local scan -> S
    gemm256<0><<<nblocks, 512, 0, stream>>>(xb, wib, b_in, h, a, bcoef, S);

    // 3. carry + replay (y overwrites h, bf16)
    scan_pass3<<<BATCH * CH, 512, 0, stream>>>(h, a, bcoef, S);

    // 4. out = y @ w_out^T + b_out  (fp32 out)
    gemm256<1><<<nblocks, 512, 0, stream>>>(h, wob, b_out, out,
                                            nullptr, nullptr, nullptr);
}